// Round 6
// baseline (1072.983 us; speedup 1.0000x reference)
//
#include <hip/hip_runtime.h>
#include <math.h>

// Problem constants (from reference)
#define HID 64      // H*C
#define NH 4
#define NC 16
#define EDIM 16
#define OUTD 128
#define NEG 0.2f

typedef float v4f __attribute__((ext_vector_type(4)));   // native vector for nontemporal builtins

// CSR: slot p has csr_src[p] (source node) and csr_ea[p] (16 floats, 64B).
// Slot offs[d] is the self-loop (attr = mean of in-edge attrs); offs[d]+1.. in-edges.

// ---------------- CSR build ----------------

__global__ void hist_kernel(const int* __restrict__ dst, int* __restrict__ deg, int E) {
    int e = blockIdx.x * 256 + threadIdx.x;
    if (e < E) atomicAdd(&deg[dst[e]], 1);
}

__global__ void scan_a(const int* __restrict__ deg, int* __restrict__ offs,
                       int* __restrict__ bsum, int n) {
    __shared__ int tmp[1024];
    int i = blockIdx.x * 1024 + threadIdx.x;
    int v = (i < n) ? (deg[i] + 1) : 0;      // +1: self-loop slot
    tmp[threadIdx.x] = v;
    __syncthreads();
    for (int off = 1; off < 1024; off <<= 1) {
        int t = (threadIdx.x >= off) ? tmp[threadIdx.x - off] : 0;
        __syncthreads();
        tmp[threadIdx.x] += t;
        __syncthreads();
    }
    if (i < n) offs[i] = tmp[threadIdx.x] - v;   // exclusive
    if (threadIdx.x == 1023) bsum[blockIdx.x] = tmp[1023];
}

__global__ void scan_b(int* __restrict__ bsum, int* __restrict__ offs, int nb, int n) {
    __shared__ int tmp[1024];
    int v = (threadIdx.x < nb) ? bsum[threadIdx.x] : 0;
    tmp[threadIdx.x] = v;
    __syncthreads();
    for (int off = 1; off < 1024; off <<= 1) {
        int t = (threadIdx.x >= off) ? tmp[threadIdx.x - off] : 0;
        __syncthreads();
        tmp[threadIdx.x] += t;
        __syncthreads();
    }
    if (threadIdx.x < nb) bsum[threadIdx.x] = tmp[threadIdx.x] - v;  // exclusive
    if (threadIdx.x == 1023) offs[n] = tmp[1023];                    // total = E + N
}

__global__ void scan_c(int* __restrict__ offs, const int* __restrict__ bsum, int n) {
    int i = blockIdx.x * 1024 + threadIdx.x;
    if (i < n) offs[i] += bsum[blockIdx.x];
}

// scatter: fill in-edge slots; copy edge attr into CSR order (sequential read,
// random 64B nontemporal write — paid once, read sequentially twice)
__global__ void scatter_kernel(const int* __restrict__ src, const int* __restrict__ dst,
                               const v4f* __restrict__ ea,
                               const int* __restrict__ offs, int* __restrict__ cursor,
                               int* __restrict__ csr_src, v4f* __restrict__ csr_ea,
                               int E) {
    int e = blockIdx.x * 256 + threadIdx.x;
    if (e >= E) return;
    int d = dst[e];
    int p = offs[d] + 1 + atomicAdd(&cursor[d], 1);
    csr_src[p] = src[e];
    v4f a0 = ea[e * 4 + 0], a1 = ea[e * 4 + 1],
        a2 = ea[e * 4 + 2], a3 = ea[e * 4 + 3];
    __builtin_nontemporal_store(a0, &csr_ea[p * 4 + 0]);
    __builtin_nontemporal_store(a1, &csr_ea[p * 4 + 1]);
    __builtin_nontemporal_store(a2, &csr_ea[p * 4 + 2]);
    __builtin_nontemporal_store(a3, &csr_ea[p * 4 + 3]);
}

// self-loop slot: attr = mean of in-edge attrs (0 if none), src = node itself
__global__ void loopattr_kernel(const int* __restrict__ offs, int* __restrict__ csr_src,
                                float* __restrict__ csr_ea_f, int n) {
    int idx = blockIdx.x * 256 + threadIdx.x;
    if (idx >= n * EDIM) return;
    int nd = idx >> 4, k = idx & 15;
    int e0 = offs[nd], e1 = offs[nd + 1];
    int deg = e1 - e0 - 1;
    float s = 0.f;
    for (int j = e0 + 1; j < e1; j++) s += csr_ea_f[(size_t)j * EDIM + k];
    csr_ea_f[(size_t)e0 * EDIM + k] = s / fmaxf((float)deg, 1.0f);
    if (k == 0) csr_src[e0] = nd;
}

// ---------------- dual GEMM: xl = x@Wl+bl, xr = x@Wr+br ----------------

__global__ __launch_bounds__(256)
void dualgemm_kernel(const float* __restrict__ x,
                     const float* __restrict__ Wl, const float* __restrict__ bl,
                     const float* __restrict__ Wr, const float* __restrict__ br,
                     float* __restrict__ xl, float* __restrict__ xr, int n) {
    __shared__ float xs[64 * 65];     // [row][k], pad 65
    __shared__ float ws[64 * 128];    // [k][j]: j<64 -> Wl col, j>=64 -> Wr col
    int tid = threadIdx.x;
    int r0 = blockIdx.x * 64;

#pragma unroll
    for (int t = 0; t < 32; t++) {
        int idx = t * 256 + tid;
        int k = idx >> 7, j = idx & 127;
        ws[idx] = (j < 64) ? Wl[k * 64 + j] : Wr[k * 64 + (j - 64)];
    }
#pragma unroll
    for (int t = 0; t < 16; t++) {
        int idx = t * 256 + tid;
        int r = idx >> 6, c = idx & 63;
        float v = (r0 + r < n) ? x[(r0 + r) * 64 + c] : 0.f;
        xs[r * 65 + c] = v;
    }
    __syncthreads();

    int cg = tid & 31;
    int rg = tid >> 5;

    float acc[8][4];
#pragma unroll
    for (int u = 0; u < 8; u++)
#pragma unroll
        for (int v = 0; v < 4; v++) acc[u][v] = 0.f;

    for (int k = 0; k < 64; k++) {
        float4 wv = *(const float4*)&ws[k * 128 + cg * 4];
        float xv[8];
#pragma unroll
        for (int u = 0; u < 8; u++) xv[u] = xs[(rg * 8 + u) * 65 + k];
#pragma unroll
        for (int u = 0; u < 8; u++) {
            acc[u][0] += xv[u] * wv.x;
            acc[u][1] += xv[u] * wv.y;
            acc[u][2] += xv[u] * wv.z;
            acc[u][3] += xv[u] * wv.w;
        }
    }

    int j0 = cg * 4;
    bool isL = (j0 < 64);
    const float* bp = isL ? bl : br;
    float* op = isL ? xl : xr;
    int jj = isL ? j0 : (j0 - 64);
    float4 bv = *(const float4*)&bp[jj];
#pragma unroll
    for (int u = 0; u < 8; u++) {
        int r = r0 + rg * 8 + u;
        if (r < n) {
            float4 o;
            o.x = acc[u][0] + bv.x; o.y = acc[u][1] + bv.y;
            o.z = acc[u][2] + bv.z; o.w = acc[u][3] + bv.w;
            *(float4*)&op[r * 64 + jj] = o;
        }
    }
}

// ---------------- GATv2 layer ----------------
// One wave per dst node, lane = h*16+c. Attr + src loads are uniform (scalar);
// gathers use scalar row base + fixed lane offset (no per-edge VALU addr math).
// Prefetch one pair ahead, UNCONDITIONALLY with clamped index (no exec toggling).

#define DOT16(P0, P1, P2, P3)                                              \
    (P0.x*wec[0] + P0.y*wec[1] + P0.z*wec[2] + P0.w*wec[3]                 \
   + P1.x*wec[4] + P1.y*wec[5] + P1.z*wec[6] + P1.w*wec[7]                 \
   + P2.x*wec[8] + P2.y*wec[9] + P2.z*wec[10] + P2.w*wec[11]               \
   + P3.x*wec[12] + P3.y*wec[13] + P3.z*wec[14] + P3.w*wec[15])

__global__ __launch_bounds__(256)
void gat_kernel(const int* __restrict__ offs, const int* __restrict__ csr_src,
                const float4* __restrict__ csr_ea,
                const float* __restrict__ xl, const float* __restrict__ xr,
                const float* __restrict__ We, const float* __restrict__ att,
                const float* __restrict__ bias, float* __restrict__ out, int n) {
    int lane = threadIdx.x & 63;
    int node = __builtin_amdgcn_readfirstlane(blockIdx.x * 4 + (threadIdx.x >> 6));
    if (node >= n) return;

    float wec[16];
#pragma unroll
    for (int k = 0; k < 16; k++) wec[k] = We[k * 64 + lane];
    const float LOG2E = 1.4426950408889634f;
    float attl = att[lane] * LOG2E;
    float xrl = xr[(size_t)node * 64 + lane];

    int e0 = __builtin_amdgcn_readfirstlane(offs[node]);
    int e1 = __builtin_amdgcn_readfirstlane(offs[node + 1]);

    float M = -1e30f, S = 0.f, acc = 0.f;
    int i = e0;

    if ((e1 - e0) & 1) {            // odd count: process slot e0 (self-loop) alone
        int s0 = csr_src[i];        // uniform -> s_load
        const float* rowa = xl + (size_t)s0 * 64;
        float4 A0 = csr_ea[i*4+0], A1 = csr_ea[i*4+1],
               A2 = csr_ea[i*4+2], A3 = csr_ea[i*4+3];
        float x0 = rowa[lane];
        float m0 = x0 + xrl + DOT16(A0, A1, A2, A3);
        m0 = fmaxf(m0, NEG * m0);
        float p0 = m0 * attl;
        p0 += __shfl_xor(p0, 1);
        p0 += __shfl_xor(p0, 2);
        p0 += __shfl_xor(p0, 4);
        p0 += __shfl_xor(p0, 8);
        M = p0; S = 1.f; acc = x0;   // first edge: z=1
        i++;
    }

    if (i < e1) {                    // remaining count is even, >= 2
        int sa = csr_src[i], sb = csr_src[i + 1];
        float4 A0 = csr_ea[i*4+0], A1 = csr_ea[i*4+1],
               A2 = csr_ea[i*4+2], A3 = csr_ea[i*4+3];
        float4 B0 = csr_ea[i*4+4], B1 = csr_ea[i*4+5],
               B2 = csr_ea[i*4+6], B3 = csr_ea[i*4+7];
        float xa = (xl + (size_t)sa * 64)[lane];
        float xb = (xl + (size_t)sb * 64)[lane];
        int last = e1 - 2;           // uniform
        for (;;) {
            int j = i + 2;
            j = (j > last) ? last : j;            // clamp: always-valid prefetch
            int sa_n = csr_src[j], sb_n = csr_src[j + 1];
            float4 A0n = csr_ea[j*4+0], A1n = csr_ea[j*4+1],
                   A2n = csr_ea[j*4+2], A3n = csr_ea[j*4+3];
            float4 B0n = csr_ea[j*4+4], B1n = csr_ea[j*4+5],
                   B2n = csr_ea[j*4+6], B3n = csr_ea[j*4+7];
            float xa_n = (xl + (size_t)sa_n * 64)[lane];
            float xb_n = (xl + (size_t)sb_n * 64)[lane];

            // compute current pair
            float m0 = xa + xrl + DOT16(A0, A1, A2, A3);
            float m1 = xb + xrl + DOT16(B0, B1, B2, B3);
            m0 = fmaxf(m0, NEG * m0);
            m1 = fmaxf(m1, NEG * m1);
            float p0 = m0 * attl;
            float p1 = m1 * attl;
            p0 += __shfl_xor(p0, 1);  p1 += __shfl_xor(p1, 1);
            p0 += __shfl_xor(p0, 2);  p1 += __shfl_xor(p1, 2);
            p0 += __shfl_xor(p0, 4);  p1 += __shfl_xor(p1, 4);
            p0 += __shfl_xor(p0, 8);  p1 += __shfl_xor(p1, 8);
            float Mn = fmaxf(M, fmaxf(p0, p1));
            float fs = __builtin_amdgcn_exp2f(M - Mn);
            float z0 = __builtin_amdgcn_exp2f(p0 - Mn);
            float z1 = __builtin_amdgcn_exp2f(p1 - Mn);
            S   = S * fs + z0 + z1;
            acc = acc * fs + z0 * xa + z1 * xb;
            M = Mn;

            if (i >= last) break;
            i = j;
            sa = sa_n; sb = sb_n;
            A0 = A0n; A1 = A1n; A2 = A2n; A3 = A3n;
            B0 = B0n; B1 = B1n; B2 = B2n; B3 = B3n;
            xa = xa_n; xb = xb_n;
        }
    }
    out[(size_t)node * 64 + lane] = fmaxf(acc / S + bias[lane], 0.f);
}

// ---------------- fused pool (batch is sorted) + MLP: one block per graph ----------------

__global__ __launch_bounds__(256)
void pool_mlp_kernel(const float* __restrict__ x, const int* __restrict__ batch, int n,
                     const float* __restrict__ W1, const float* __restrict__ b1,
                     const float* __restrict__ W2, const float* __restrict__ b2,
                     float* __restrict__ out) {
    __shared__ float psum[4][64];
    __shared__ float gv[64];
    __shared__ float hid[128];
    __shared__ int bounds[2];

    int g = blockIdx.x;
    int tid = threadIdx.x;
    int wave = tid >> 6, lane = tid & 63;

    if (tid < 2) {
        int target = g + tid;
        int lo = 0, hi = n;
        while (lo < hi) {
            int mid = (lo + hi) >> 1;
            if (batch[mid] < target) lo = mid + 1; else hi = mid;
        }
        bounds[tid] = lo;
    }
    __syncthreads();
    int lo = bounds[0], hi = bounds[1];
    int cnt = hi - lo;

    float s = 0.f;
    for (int nd = lo + wave; nd < hi; nd += 4)
        s += x[(size_t)nd * 64 + lane];
    psum[wave][lane] = s;
    __syncthreads();

    if (tid < 64)
        gv[tid] = (psum[0][tid] + psum[1][tid] + psum[2][tid] + psum[3][tid])
                  / fmaxf((float)cnt, 1.0f);
    __syncthreads();

    if (tid < 128) {
        float h = b1[tid];
        for (int k = 0; k < 64; k++) h += gv[k] * W1[k * 128 + tid];
        hid[tid] = fmaxf(h, 0.f);
    }
    __syncthreads();
    if (tid < 128) {
        float o = b2[tid];
        for (int k = 0; k < 128; k++) o += hid[k] * W2[k * 128 + tid];
        out[g * 128 + tid] = o;
    }
}

// ---------------- launch ----------------

extern "C" void kernel_launch(void* const* d_in, const int* in_sizes, int n_in,
                              void* d_out, int out_size, void* d_ws, size_t ws_size,
                              hipStream_t stream) {
    const float* nf   = (const float*)d_in[0];
    const int*   ei   = (const int*)d_in[1];
    const float* eaw  = (const float*)d_in[2];
    const int*   bat  = (const int*)d_in[3];
    const float* l0_Wl = (const float*)d_in[4];
    const float* l0_bl = (const float*)d_in[5];
    const float* l0_Wr = (const float*)d_in[6];
    const float* l0_br = (const float*)d_in[7];
    const float* l0_We = (const float*)d_in[8];
    const float* l0_att = (const float*)d_in[9];
    const float* l0_bias = (const float*)d_in[10];
    const float* l1_Wl = (const float*)d_in[11];
    const float* l1_bl = (const float*)d_in[12];
    const float* l1_Wr = (const float*)d_in[13];
    const float* l1_br = (const float*)d_in[14];
    const float* l1_We = (const float*)d_in[15];
    const float* l1_att = (const float*)d_in[16];
    const float* l1_bias = (const float*)d_in[17];
    const float* mW1 = (const float*)d_in[18];
    const float* mb1 = (const float*)d_in[19];
    const float* mW2 = (const float*)d_in[20];
    const float* mb2 = (const float*)d_in[21];

    const int N = in_sizes[0] / 64;
    const int E = in_sizes[1] / 2;
    const int G = out_size / OUTD;

    char* w = (char*)d_ws;
    auto carve = [&](size_t bytes) {
        void* p = (void*)w;
        w += (bytes + 255) & ~(size_t)255;
        return p;
    };
    int*    deg     = (int*)carve((size_t)N * 4);
    int*    offs    = (int*)carve((size_t)(N + 1) * 4);
    int*    cursor  = (int*)carve((size_t)N * 4);
    int*    bsum    = (int*)carve(4096 * 4);
    int*    csr_src = (int*)carve((size_t)(E + N) * 4);
    v4f*    csr_ea  = (v4f*)carve((size_t)(E + N) * 64);
    float*  xl      = (float*)carve((size_t)N * 64 * 4);
    float*  xr      = (float*)carve((size_t)N * 64 * 4);
    float*  x1      = (float*)carve((size_t)N * 64 * 4);

    hipMemsetAsync(deg, 0, (size_t)N * 4, stream);
    hipMemsetAsync(cursor, 0, (size_t)N * 4, stream);

    const int* src = ei;
    const int* dst = ei + E;

    hist_kernel<<<(E + 255) / 256, 256, 0, stream>>>(dst, deg, E);

    int nb = (N + 1023) / 1024;
    scan_a<<<nb, 1024, 0, stream>>>(deg, offs, bsum, N);
    scan_b<<<1, 1024, 0, stream>>>(bsum, offs, nb, N);
    scan_c<<<nb, 1024, 0, stream>>>(offs, bsum, N);

    scatter_kernel<<<(E + 255) / 256, 256, 0, stream>>>(src, dst, (const v4f*)eaw,
                                                        offs, cursor, csr_src, csr_ea, E);
    loopattr_kernel<<<(N * EDIM + 255) / 256, 256, 0, stream>>>(offs, csr_src,
                                                                (float*)csr_ea, N);

    // layer 0
    dualgemm_kernel<<<(N + 63) / 64, 256, 0, stream>>>(nf, l0_Wl, l0_bl, l0_Wr, l0_br,
                                                       xl, xr, N);
    gat_kernel<<<(N + 3) / 4, 256, 0, stream>>>(offs, csr_src, (const float4*)csr_ea,
                                                xl, xr, l0_We, l0_att, l0_bias, x1, N);
    // layer 1
    dualgemm_kernel<<<(N + 63) / 64, 256, 0, stream>>>(x1, l1_Wl, l1_bl, l1_Wr, l1_br,
                                                       xl, xr, N);
    gat_kernel<<<(N + 3) / 4, 256, 0, stream>>>(offs, csr_src, (const float4*)csr_ea,
                                                xl, xr, l1_We, l1_att, l1_bias, x1, N);

    // fused pool + MLP
    pool_mlp_kernel<<<G, 256, 0, stream>>>(x1, bat, N, mW1, mb1, mW2, mb2, (float*)d_out);
}

// Round 7
// 831.283 us; speedup vs baseline: 1.2908x; 1.2908x over previous
//
#include <hip/hip_runtime.h>
#include <math.h>

// Problem constants (from reference)
#define HID 64      // H*C
#define NH 4
#define NC 16
#define EDIM 16
#define OUTD 128
#define NEG 0.2f

typedef float v4f __attribute__((ext_vector_type(4)));
typedef float v2f __attribute__((ext_vector_type(2)));

// packed fp32 fma (v_pk_fma_f32 on gfx950)
__device__ __forceinline__ v2f pkfma(v2f a, v2f b, v2f c) {
    return __builtin_elementwise_fma(a, b, c);
}

// DPP butterfly add over 16-lane group (quad_perm xor1, xor2, row_ror:4, row_ror:8)
template <int CTRL>
__device__ __forceinline__ float dpp_add(float x) {
    int t = __builtin_amdgcn_update_dpp(0, __float_as_int(x), CTRL, 0xF, 0xF, true);
    return x + __int_as_float(t);
}
__device__ __forceinline__ float red16(float x) {
    x = dpp_add<0xB1>(x);    // quad_perm [1,0,3,2]  (xor 1)
    x = dpp_add<0x4E>(x);    // quad_perm [2,3,0,1]  (xor 2)
    x = dpp_add<0x124>(x);   // row_ror:4
    x = dpp_add<0x128>(x);   // row_ror:8
    return x;
}

// CSR: slot p has csr_src[p] (source node) and csr_ea[p] (16 floats, 64B).
// Slot offs[d] is the self-loop (attr = mean of in-edge attrs); offs[d]+1.. in-edges.

// ---------------- CSR build ----------------

__global__ void hist_kernel(const int* __restrict__ dst, int* __restrict__ deg, int E) {
    int e = blockIdx.x * 256 + threadIdx.x;
    if (e < E) atomicAdd(&deg[dst[e]], 1);
}

__global__ void scan_a(const int* __restrict__ deg, int* __restrict__ offs,
                       int* __restrict__ bsum, int n) {
    __shared__ int tmp[1024];
    int i = blockIdx.x * 1024 + threadIdx.x;
    int v = (i < n) ? (deg[i] + 1) : 0;      // +1: self-loop slot
    tmp[threadIdx.x] = v;
    __syncthreads();
    for (int off = 1; off < 1024; off <<= 1) {
        int t = (threadIdx.x >= off) ? tmp[threadIdx.x - off] : 0;
        __syncthreads();
        tmp[threadIdx.x] += t;
        __syncthreads();
    }
    if (i < n) offs[i] = tmp[threadIdx.x] - v;   // exclusive
    if (threadIdx.x == 1023) bsum[blockIdx.x] = tmp[1023];
}

__global__ void scan_b(int* __restrict__ bsum, int* __restrict__ offs, int nb, int n) {
    __shared__ int tmp[1024];
    int v = (threadIdx.x < nb) ? bsum[threadIdx.x] : 0;
    tmp[threadIdx.x] = v;
    __syncthreads();
    for (int off = 1; off < 1024; off <<= 1) {
        int t = (threadIdx.x >= off) ? tmp[threadIdx.x - off] : 0;
        __syncthreads();
        tmp[threadIdx.x] += t;
        __syncthreads();
    }
    if (threadIdx.x < nb) bsum[threadIdx.x] = tmp[threadIdx.x] - v;  // exclusive
    if (threadIdx.x == 1023) offs[n] = tmp[1023];                    // total = E + N
}

__global__ void scan_c(int* __restrict__ offs, const int* __restrict__ bsum, int n) {
    int i = blockIdx.x * 1024 + threadIdx.x;
    if (i < n) offs[i] += bsum[blockIdx.x];
}

// scatter: fill in-edge slots; copy edge attr into CSR order.
// Plain cached stores: L2 coalesces the random 64B writes (nt stores regressed 2x).
__global__ void scatter_kernel(const int* __restrict__ src, const int* __restrict__ dst,
                               const v4f* __restrict__ ea,
                               const int* __restrict__ offs, int* __restrict__ cursor,
                               int* __restrict__ csr_src, v4f* __restrict__ csr_ea,
                               int E) {
    int e = blockIdx.x * 256 + threadIdx.x;
    if (e >= E) return;
    int d = dst[e];
    int p = offs[d] + 1 + atomicAdd(&cursor[d], 1);
    csr_src[p] = src[e];
    v4f a0 = ea[e * 4 + 0], a1 = ea[e * 4 + 1],
        a2 = ea[e * 4 + 2], a3 = ea[e * 4 + 3];
    csr_ea[p * 4 + 0] = a0;
    csr_ea[p * 4 + 1] = a1;
    csr_ea[p * 4 + 2] = a2;
    csr_ea[p * 4 + 3] = a3;
}

// self-loop slot: attr = mean of in-edge attrs (0 if none), src = node itself
__global__ void loopattr_kernel(const int* __restrict__ offs, int* __restrict__ csr_src,
                                float* __restrict__ csr_ea_f, int n) {
    int idx = blockIdx.x * 256 + threadIdx.x;
    if (idx >= n * EDIM) return;
    int nd = idx >> 4, k = idx & 15;
    int e0 = offs[nd], e1 = offs[nd + 1];
    int deg = e1 - e0 - 1;
    float s = 0.f;
    for (int j = e0 + 1; j < e1; j++) s += csr_ea_f[(size_t)j * EDIM + k];
    csr_ea_f[(size_t)e0 * EDIM + k] = s / fmaxf((float)deg, 1.0f);
    if (k == 0) csr_src[e0] = nd;
}

// ---------------- dual GEMM: xl = x@Wl+bl, xr = x@Wr+br ----------------

__global__ __launch_bounds__(256)
void dualgemm_kernel(const float* __restrict__ x,
                     const float* __restrict__ Wl, const float* __restrict__ bl,
                     const float* __restrict__ Wr, const float* __restrict__ br,
                     float* __restrict__ xl, float* __restrict__ xr, int n) {
    __shared__ float xs[64 * 65];     // [row][k], pad 65
    __shared__ float ws[64 * 128];    // [k][j]: j<64 -> Wl col, j>=64 -> Wr col
    int tid = threadIdx.x;
    int r0 = blockIdx.x * 64;

#pragma unroll
    for (int t = 0; t < 32; t++) {
        int idx = t * 256 + tid;
        int k = idx >> 7, j = idx & 127;
        ws[idx] = (j < 64) ? Wl[k * 64 + j] : Wr[k * 64 + (j - 64)];
    }
#pragma unroll
    for (int t = 0; t < 16; t++) {
        int idx = t * 256 + tid;
        int r = idx >> 6, c = idx & 63;
        float v = (r0 + r < n) ? x[(r0 + r) * 64 + c] : 0.f;
        xs[r * 65 + c] = v;
    }
    __syncthreads();

    int cg = tid & 31;
    int rg = tid >> 5;

    float acc[8][4];
#pragma unroll
    for (int u = 0; u < 8; u++)
#pragma unroll
        for (int v = 0; v < 4; v++) acc[u][v] = 0.f;

    for (int k = 0; k < 64; k++) {
        float4 wv = *(const float4*)&ws[k * 128 + cg * 4];
        float xv[8];
#pragma unroll
        for (int u = 0; u < 8; u++) xv[u] = xs[(rg * 8 + u) * 65 + k];
#pragma unroll
        for (int u = 0; u < 8; u++) {
            acc[u][0] += xv[u] * wv.x;
            acc[u][1] += xv[u] * wv.y;
            acc[u][2] += xv[u] * wv.z;
            acc[u][3] += xv[u] * wv.w;
        }
    }

    int j0 = cg * 4;
    bool isL = (j0 < 64);
    const float* bp = isL ? bl : br;
    float* op = isL ? xl : xr;
    int jj = isL ? j0 : (j0 - 64);
    float4 bv = *(const float4*)&bp[jj];
#pragma unroll
    for (int u = 0; u < 8; u++) {
        int r = r0 + rg * 8 + u;
        if (r < n) {
            float4 o;
            o.x = acc[u][0] + bv.x; o.y = acc[u][1] + bv.y;
            o.z = acc[u][2] + bv.z; o.w = acc[u][3] + bv.w;
            *(float4*)&op[r * 64 + jj] = o;
        }
    }
}

// ---------------- GATv2 layer ----------------
// One wave per dst node, lane = h*16+c. Attr + src loads uniform (scalar);
// gathers via scalar row base + lane offset. Prefetch one pair ahead (clamped).
// Packed-fp32 dot (v_pk_fma_f32), DPP butterfly reduce, no-max softmax
// (scores bounded ~|10| << fp32 exp2 range; softmax shift-invariant).

// 16-term dot: attr (uniform) . wec[lane], packed 2-wide; init folded in .x
#define EDOT(A0, A1, A2, A3, INIT)                                         \
    ({ v2f _a = {(INIT), 0.f};                                             \
       _a = pkfma((v2f){A0.x, A0.y}, wec2[0], _a);                         \
       _a = pkfma((v2f){A0.z, A0.w}, wec2[1], _a);                         \
       _a = pkfma((v2f){A1.x, A1.y}, wec2[2], _a);                         \
       _a = pkfma((v2f){A1.z, A1.w}, wec2[3], _a);                         \
       _a = pkfma((v2f){A2.x, A2.y}, wec2[4], _a);                         \
       _a = pkfma((v2f){A2.z, A2.w}, wec2[5], _a);                         \
       _a = pkfma((v2f){A3.x, A3.y}, wec2[6], _a);                         \
       _a = pkfma((v2f){A3.z, A3.w}, wec2[7], _a);                         \
       _a.x + _a.y; })

__global__ __launch_bounds__(256)
void gat_kernel(const int* __restrict__ offs, const int* __restrict__ csr_src,
                const float4* __restrict__ csr_ea,
                const float* __restrict__ xl, const float* __restrict__ xr,
                const float* __restrict__ We, const float* __restrict__ att,
                const float* __restrict__ bias, float* __restrict__ out, int n) {
    int lane = threadIdx.x & 63;
    int node = __builtin_amdgcn_readfirstlane(blockIdx.x * 4 + (threadIdx.x >> 6));
    if (node >= n) return;

    v2f wec2[8];
#pragma unroll
    for (int k = 0; k < 8; k++) {
        wec2[k].x = We[(2 * k) * 64 + lane];
        wec2[k].y = We[(2 * k + 1) * 64 + lane];
    }
    const float LOG2E = 1.4426950408889634f;
    float attl = att[lane] * LOG2E;
    float xrl = xr[(size_t)node * 64 + lane];

    int e0 = __builtin_amdgcn_readfirstlane(offs[node]);
    int e1 = __builtin_amdgcn_readfirstlane(offs[node + 1]);

    float S = 0.f, acc = 0.f;
    int i = e0;

    if ((e1 - e0) & 1) {            // odd count: process slot e0 (self-loop) alone
        int s0 = csr_src[i];        // uniform -> s_load
        float4 A0 = csr_ea[i*4+0], A1 = csr_ea[i*4+1],
               A2 = csr_ea[i*4+2], A3 = csr_ea[i*4+3];
        float x0 = (xl + (size_t)s0 * 64)[lane];
        float m0 = EDOT(A0, A1, A2, A3, x0 + xrl);
        m0 = fmaxf(m0, NEG * m0);
        float p0 = red16(m0 * attl);
        float z0 = __builtin_amdgcn_exp2f(p0);
        S = z0; acc = z0 * x0;
        i++;
    }

    if (i < e1) {                    // remaining count is even, >= 2
        int sa = csr_src[i], sb = csr_src[i + 1];
        float4 A0 = csr_ea[i*4+0], A1 = csr_ea[i*4+1],
               A2 = csr_ea[i*4+2], A3 = csr_ea[i*4+3];
        float4 B0 = csr_ea[i*4+4], B1 = csr_ea[i*4+5],
               B2 = csr_ea[i*4+6], B3 = csr_ea[i*4+7];
        float xa = (xl + (size_t)sa * 64)[lane];
        float xb = (xl + (size_t)sb * 64)[lane];
        int last = e1 - 2;           // uniform
        for (;;) {
            int j = i + 2;
            j = (j > last) ? last : j;            // clamp: always-valid prefetch
            int sa_n = csr_src[j], sb_n = csr_src[j + 1];
            float4 A0n = csr_ea[j*4+0], A1n = csr_ea[j*4+1],
                   A2n = csr_ea[j*4+2], A3n = csr_ea[j*4+3];
            float4 B0n = csr_ea[j*4+4], B1n = csr_ea[j*4+5],
                   B2n = csr_ea[j*4+6], B3n = csr_ea[j*4+7];
            float xa_n = (xl + (size_t)sa_n * 64)[lane];
            float xb_n = (xl + (size_t)sb_n * 64)[lane];

            // compute current pair
            float m0 = EDOT(A0, A1, A2, A3, xa + xrl);
            float m1 = EDOT(B0, B1, B2, B3, xb + xrl);
            m0 = fmaxf(m0, NEG * m0);
            m1 = fmaxf(m1, NEG * m1);
            float p0 = red16(m0 * attl);
            float p1 = red16(m1 * attl);
            float z0 = __builtin_amdgcn_exp2f(p0);
            float z1 = __builtin_amdgcn_exp2f(p1);
            S += z0 + z1;
            acc = fmaf(z0, xa, fmaf(z1, xb, acc));

            if (i >= last) break;
            i = j;
            sa = sa_n; sb = sb_n;
            A0 = A0n; A1 = A1n; A2 = A2n; A3 = A3n;
            B0 = B0n; B1 = B1n; B2 = B2n; B3 = B3n;
            xa = xa_n; xb = xb_n;
        }
    }
    out[(size_t)node * 64 + lane] = fmaxf(acc / S + bias[lane], 0.f);
}

// ---------------- fused pool (batch is sorted) + MLP: one block per graph ----------------

__global__ __launch_bounds__(256)
void pool_mlp_kernel(const float* __restrict__ x, const int* __restrict__ batch, int n,
                     const float* __restrict__ W1, const float* __restrict__ b1,
                     const float* __restrict__ W2, const float* __restrict__ b2,
                     float* __restrict__ out) {
    __shared__ float psum[4][64];
    __shared__ float gv[64];
    __shared__ float hid[128];
    __shared__ int bounds[2];

    int g = blockIdx.x;
    int tid = threadIdx.x;
    int wave = tid >> 6, lane = tid & 63;

    if (tid < 2) {
        int target = g + tid;
        int lo = 0, hi = n;
        while (lo < hi) {
            int mid = (lo + hi) >> 1;
            if (batch[mid] < target) lo = mid + 1; else hi = mid;
        }
        bounds[tid] = lo;
    }
    __syncthreads();
    int lo = bounds[0], hi = bounds[1];
    int cnt = hi - lo;

    float s = 0.f;
    for (int nd = lo + wave; nd < hi; nd += 4)
        s += x[(size_t)nd * 64 + lane];
    psum[wave][lane] = s;
    __syncthreads();

    if (tid < 64)
        gv[tid] = (psum[0][tid] + psum[1][tid] + psum[2][tid] + psum[3][tid])
                  / fmaxf((float)cnt, 1.0f);
    __syncthreads();

    if (tid < 128) {
        float h = b1[tid];
        for (int k = 0; k < 64; k++) h += gv[k] * W1[k * 128 + tid];
        hid[tid] = fmaxf(h, 0.f);
    }
    __syncthreads();
    if (tid < 128) {
        float o = b2[tid];
        for (int k = 0; k < 128; k++) o += hid[k] * W2[k * 128 + tid];
        out[g * 128 + tid] = o;
    }
}

// ---------------- launch ----------------

extern "C" void kernel_launch(void* const* d_in, const int* in_sizes, int n_in,
                              void* d_out, int out_size, void* d_ws, size_t ws_size,
                              hipStream_t stream) {
    const float* nf   = (const float*)d_in[0];
    const int*   ei   = (const int*)d_in[1];
    const float* eaw  = (const float*)d_in[2];
    const int*   bat  = (const int*)d_in[3];
    const float* l0_Wl = (const float*)d_in[4];
    const float* l0_bl = (const float*)d_in[5];
    const float* l0_Wr = (const float*)d_in[6];
    const float* l0_br = (const float*)d_in[7];
    const float* l0_We = (const float*)d_in[8];
    const float* l0_att = (const float*)d_in[9];
    const float* l0_bias = (const float*)d_in[10];
    const float* l1_Wl = (const float*)d_in[11];
    const float* l1_bl = (const float*)d_in[12];
    const float* l1_Wr = (const float*)d_in[13];
    const float* l1_br = (const float*)d_in[14];
    const float* l1_We = (const float*)d_in[15];
    const float* l1_att = (const float*)d_in[16];
    const float* l1_bias = (const float*)d_in[17];
    const float* mW1 = (const float*)d_in[18];
    const float* mb1 = (const float*)d_in[19];
    const float* mW2 = (const float*)d_in[20];
    const float* mb2 = (const float*)d_in[21];

    const int N = in_sizes[0] / 64;
    const int E = in_sizes[1] / 2;
    const int G = out_size / OUTD;

    char* w = (char*)d_ws;
    auto carve = [&](size_t bytes) {
        void* p = (void*)w;
        w += (bytes + 255) & ~(size_t)255;
        return p;
    };
    int*    deg     = (int*)carve((size_t)N * 4);
    int*    offs    = (int*)carve((size_t)(N + 1) * 4);
    int*    cursor  = (int*)carve((size_t)N * 4);
    int*    bsum    = (int*)carve(4096 * 4);
    int*    csr_src = (int*)carve((size_t)(E + N) * 4);
    v4f*    csr_ea  = (v4f*)carve((size_t)(E + N) * 64);
    float*  xl      = (float*)carve((size_t)N * 64 * 4);
    float*  xr      = (float*)carve((size_t)N * 64 * 4);
    float*  x1      = (float*)carve((size_t)N * 64 * 4);

    hipMemsetAsync(deg, 0, (size_t)N * 4, stream);
    hipMemsetAsync(cursor, 0, (size_t)N * 4, stream);

    const int* src = ei;
    const int* dst = ei + E;

    hist_kernel<<<(E + 255) / 256, 256, 0, stream>>>(dst, deg, E);

    int nb = (N + 1023) / 1024;
    scan_a<<<nb, 1024, 0, stream>>>(deg, offs, bsum, N);
    scan_b<<<1, 1024, 0, stream>>>(bsum, offs, nb, N);
    scan_c<<<nb, 1024, 0, stream>>>(offs, bsum, N);

    scatter_kernel<<<(E + 255) / 256, 256, 0, stream>>>(src, dst, (const v4f*)eaw,
                                                        offs, cursor, csr_src, csr_ea, E);
    loopattr_kernel<<<(N * EDIM + 255) / 256, 256, 0, stream>>>(offs, csr_src,
                                                                (float*)csr_ea, N);

    // layer 0
    dualgemm_kernel<<<(N + 63) / 64, 256, 0, stream>>>(nf, l0_Wl, l0_bl, l0_Wr, l0_br,
                                                       xl, xr, N);
    gat_kernel<<<(N + 3) / 4, 256, 0, stream>>>(offs, csr_src, (const float4*)csr_ea,
                                                xl, xr, l0_We, l0_att, l0_bias, x1, N);
    // layer 1
    dualgemm_kernel<<<(N + 63) / 64, 256, 0, stream>>>(x1, l1_Wl, l1_bl, l1_Wr, l1_br,
                                                       xl, xr, N);
    gat_kernel<<<(N + 3) / 4, 256, 0, stream>>>(offs, csr_src, (const float4*)csr_ea,
                                                xl, xr, l1_We, l1_att, l1_bias, x1, N);

    // fused pool + MLP
    pool_mlp_kernel<<<G, 256, 0, stream>>>(x1, bat, N, mW1, mb1, mW2, mb2, (float*)d_out);
}

// Round 8
// 803.643 us; speedup vs baseline: 1.3351x; 1.0344x over previous
//
#include <hip/hip_runtime.h>
#include <math.h>

// Problem constants (from reference)
#define HID 64      // H*C
#define NH 4
#define NC 16
#define EDIM 16
#define OUTD 128
#define NEG 0.2f

typedef float v4f __attribute__((ext_vector_type(4)));
typedef float v2f __attribute__((ext_vector_type(2)));

// packed fp32 fma (v_pk_fma_f32 on gfx950)
__device__ __forceinline__ v2f pkfma(v2f a, v2f b, v2f c) {
    return __builtin_elementwise_fma(a, b, c);
}

// DPP butterfly add over 16-lane group (quad_perm xor1, xor2, row_ror:4, row_ror:8)
template <int CTRL>
__device__ __forceinline__ float dpp_add(float x) {
    int t = __builtin_amdgcn_update_dpp(0, __float_as_int(x), CTRL, 0xF, 0xF, true);
    return x + __int_as_float(t);
}
__device__ __forceinline__ float red16(float x) {
    x = dpp_add<0xB1>(x);    // quad_perm [1,0,3,2]  (xor 1)
    x = dpp_add<0x4E>(x);    // quad_perm [2,3,0,1]  (xor 2)
    x = dpp_add<0x124>(x);   // row_ror:4
    x = dpp_add<0x128>(x);   // row_ror:8
    return x;
}

// CSR: slot p has csr_src[p] (source node) and csr_ea[p] (16 floats, 64B).
// Slot offs[d] is the self-loop (attr = mean of in-edge attrs); offs[d]+1.. in-edges.

// ---------------- CSR build ----------------

// hist also emits rank[e] = arrival rank of edge e within its dst bucket
// (the atomicAdd return value) so scatter needs NO atomic (was latency-bound).
__global__ void hist_kernel(const int* __restrict__ dst, int* __restrict__ deg,
                            int* __restrict__ rank, int E) {
    int e = blockIdx.x * 256 + threadIdx.x;
    if (e < E) rank[e] = atomicAdd(&deg[dst[e]], 1);
}

__global__ void scan_a(const int* __restrict__ deg, int* __restrict__ offs,
                       int* __restrict__ bsum, int n) {
    __shared__ int tmp[1024];
    int i = blockIdx.x * 1024 + threadIdx.x;
    int v = (i < n) ? (deg[i] + 1) : 0;      // +1: self-loop slot
    tmp[threadIdx.x] = v;
    __syncthreads();
    for (int off = 1; off < 1024; off <<= 1) {
        int t = (threadIdx.x >= off) ? tmp[threadIdx.x - off] : 0;
        __syncthreads();
        tmp[threadIdx.x] += t;
        __syncthreads();
    }
    if (i < n) offs[i] = tmp[threadIdx.x] - v;   // exclusive
    if (threadIdx.x == 1023) bsum[blockIdx.x] = tmp[1023];
}

__global__ void scan_b(int* __restrict__ bsum, int* __restrict__ offs, int nb, int n) {
    __shared__ int tmp[1024];
    int v = (threadIdx.x < nb) ? bsum[threadIdx.x] : 0;
    tmp[threadIdx.x] = v;
    __syncthreads();
    for (int off = 1; off < 1024; off <<= 1) {
        int t = (threadIdx.x >= off) ? tmp[threadIdx.x - off] : 0;
        __syncthreads();
        tmp[threadIdx.x] += t;
        __syncthreads();
    }
    if (threadIdx.x < nb) bsum[threadIdx.x] = tmp[threadIdx.x] - v;  // exclusive
    if (threadIdx.x == 1023) offs[n] = tmp[1023];                    // total = E + N
}

__global__ void scan_c(int* __restrict__ offs, const int* __restrict__ bsum, int n) {
    int i = blockIdx.x * 1024 + threadIdx.x;
    if (i < n) offs[i] += bsum[blockIdx.x];
}

// scatter: pure load->store now (rank precomputed in hist). Plain cached stores:
// L2 coalesces the random 64B writes (nt stores regressed 2x in R5).
__global__ void scatter_kernel(const int* __restrict__ src, const int* __restrict__ dst,
                               const int* __restrict__ rank,
                               const v4f* __restrict__ ea,
                               const int* __restrict__ offs,
                               int* __restrict__ csr_src, v4f* __restrict__ csr_ea,
                               int E) {
    int e = blockIdx.x * 256 + threadIdx.x;
    if (e >= E) return;
    int d = dst[e];
    int p = offs[d] + 1 + rank[e];
    csr_src[p] = src[e];
    v4f a0 = ea[e * 4 + 0], a1 = ea[e * 4 + 1],
        a2 = ea[e * 4 + 2], a3 = ea[e * 4 + 3];
    csr_ea[p * 4 + 0] = a0;
    csr_ea[p * 4 + 1] = a1;
    csr_ea[p * 4 + 2] = a2;
    csr_ea[p * 4 + 3] = a3;
}

// self-loop slot: attr = mean of in-edge attrs (0 if none), src = node itself
__global__ void loopattr_kernel(const int* __restrict__ offs, int* __restrict__ csr_src,
                                float* __restrict__ csr_ea_f, int n) {
    int idx = blockIdx.x * 256 + threadIdx.x;
    if (idx >= n * EDIM) return;
    int nd = idx >> 4, k = idx & 15;
    int e0 = offs[nd], e1 = offs[nd + 1];
    int deg = e1 - e0 - 1;
    float s = 0.f;
    for (int j = e0 + 1; j < e1; j++) s += csr_ea_f[(size_t)j * EDIM + k];
    csr_ea_f[(size_t)e0 * EDIM + k] = s / fmaxf((float)deg, 1.0f);
    if (k == 0) csr_src[e0] = nd;
}

// ---------------- dual GEMM: xl = x@Wl+bl, xr = x@Wr+br ----------------

__global__ __launch_bounds__(256)
void dualgemm_kernel(const float* __restrict__ x,
                     const float* __restrict__ Wl, const float* __restrict__ bl,
                     const float* __restrict__ Wr, const float* __restrict__ br,
                     float* __restrict__ xl, float* __restrict__ xr, int n) {
    __shared__ float xs[64 * 65];     // [row][k], pad 65
    __shared__ float ws[64 * 128];    // [k][j]: j<64 -> Wl col, j>=64 -> Wr col
    int tid = threadIdx.x;
    int r0 = blockIdx.x * 64;

#pragma unroll
    for (int t = 0; t < 32; t++) {
        int idx = t * 256 + tid;
        int k = idx >> 7, j = idx & 127;
        ws[idx] = (j < 64) ? Wl[k * 64 + j] : Wr[k * 64 + (j - 64)];
    }
#pragma unroll
    for (int t = 0; t < 16; t++) {
        int idx = t * 256 + tid;
        int r = idx >> 6, c = idx & 63;
        float v = (r0 + r < n) ? x[(r0 + r) * 64 + c] : 0.f;
        xs[r * 65 + c] = v;
    }
    __syncthreads();

    int cg = tid & 31;
    int rg = tid >> 5;

    float acc[8][4];
#pragma unroll
    for (int u = 0; u < 8; u++)
#pragma unroll
        for (int v = 0; v < 4; v++) acc[u][v] = 0.f;

    for (int k = 0; k < 64; k++) {
        float4 wv = *(const float4*)&ws[k * 128 + cg * 4];
        float xv[8];
#pragma unroll
        for (int u = 0; u < 8; u++) xv[u] = xs[(rg * 8 + u) * 65 + k];
#pragma unroll
        for (int u = 0; u < 8; u++) {
            acc[u][0] += xv[u] * wv.x;
            acc[u][1] += xv[u] * wv.y;
            acc[u][2] += xv[u] * wv.z;
            acc[u][3] += xv[u] * wv.w;
        }
    }

    int j0 = cg * 4;
    bool isL = (j0 < 64);
    const float* bp = isL ? bl : br;
    float* op = isL ? xl : xr;
    int jj = isL ? j0 : (j0 - 64);
    float4 bv = *(const float4*)&bp[jj];
#pragma unroll
    for (int u = 0; u < 8; u++) {
        int r = r0 + rg * 8 + u;
        if (r < n) {
            float4 o;
            o.x = acc[u][0] + bv.x; o.y = acc[u][1] + bv.y;
            o.z = acc[u][2] + bv.z; o.w = acc[u][3] + bv.w;
            *(float4*)&op[r * 64 + jj] = o;
        }
    }
}

// ---------------- GATv2 layer ----------------
// One wave per dst node, lane = h*16+c. Pair-granular 3-phase modulo-scheduled
// pipeline with static buffers (no register rotation):
//   phase t: gather(t+2) [srcs loaded at t-1], attrs(t+2), srcs(t+3), compute(t).
// All CSR loads uniform (scalar pipe); gathers = scalar row base + lane offset.

#define EDOT(A0, A1, A2, A3, INIT)                                         \
    ({ v2f _a = {(INIT), 0.f};                                             \
       _a = pkfma((v2f){A0.x, A0.y}, wec2[0], _a);                         \
       _a = pkfma((v2f){A0.z, A0.w}, wec2[1], _a);                         \
       _a = pkfma((v2f){A1.x, A1.y}, wec2[2], _a);                         \
       _a = pkfma((v2f){A1.z, A1.w}, wec2[3], _a);                         \
       _a = pkfma((v2f){A2.x, A2.y}, wec2[4], _a);                         \
       _a = pkfma((v2f){A2.z, A2.w}, wec2[5], _a);                         \
       _a = pkfma((v2f){A3.x, A3.y}, wec2[6], _a);                         \
       _a = pkfma((v2f){A3.z, A3.w}, wec2[7], _a);                         \
       _a.x + _a.y; })

// load src pair K into buffer BI
#define LOADS(K, BI) do { int _s = base + 2 * (K);                         \
    sb##BI##0 = csr_src[_s]; sb##BI##1 = csr_src[_s + 1]; } while (0)
// load attr pair K into buffer BI
#define LOADA(K, BI) do { int _q = (base + 2 * (K)) * 4;                   \
    ab##BI##0 = csr_ea[_q + 0]; ab##BI##1 = csr_ea[_q + 1];                \
    ab##BI##2 = csr_ea[_q + 2]; ab##BI##3 = csr_ea[_q + 3];                \
    ab##BI##4 = csr_ea[_q + 4]; ab##BI##5 = csr_ea[_q + 5];                \
    ab##BI##6 = csr_ea[_q + 6]; ab##BI##7 = csr_ea[_q + 7]; } while (0)
// gather x rows for buffer BI (uses srcs in buffer BI)
#define GATH(BI) do {                                                      \
    xa##BI = (xl + (size_t)sb##BI##0 * 64)[lane];                          \
    xc##BI = (xl + (size_t)sb##BI##1 * 64)[lane]; } while (0)
// compute pair from buffer BI
#define COMP(BI) do {                                                      \
    float m0 = EDOT(ab##BI##0, ab##BI##1, ab##BI##2, ab##BI##3, xa##BI + xrl); \
    float m1 = EDOT(ab##BI##4, ab##BI##5, ab##BI##6, ab##BI##7, xc##BI + xrl); \
    m0 = fmaxf(m0, NEG * m0);                                              \
    m1 = fmaxf(m1, NEG * m1);                                              \
    float p0 = red16(m0 * attl);                                           \
    float p1 = red16(m1 * attl);                                           \
    float z0 = __builtin_amdgcn_exp2f(p0);                                 \
    float z1 = __builtin_amdgcn_exp2f(p1);                                 \
    S += z0 + z1;                                                          \
    acc = fmaf(z0, xa##BI, fmaf(z1, xc##BI, acc)); } while (0)
// one pipeline phase: P = compute/src-store buffer, Q = issue buffer ((P+2)%3)
#define PHASE(P, Q) do {                                                   \
    int _k2 = t + 2; _k2 = (_k2 > lastp) ? lastp : _k2;                    \
    int _k3 = t + 3; _k3 = (_k3 > lastp) ? lastp : _k3;                    \
    GATH(Q);                                                               \
    LOADA(_k2, Q);                                                         \
    LOADS(_k3, P);                                                         \
    COMP(P); } while (0)

__global__ __launch_bounds__(256)
void gat_kernel(const int* __restrict__ offs, const int* __restrict__ csr_src,
                const float4* __restrict__ csr_ea,
                const float* __restrict__ xl, const float* __restrict__ xr,
                const float* __restrict__ We, const float* __restrict__ att,
                const float* __restrict__ bias, float* __restrict__ out, int n) {
    int lane = threadIdx.x & 63;
    int node = __builtin_amdgcn_readfirstlane(blockIdx.x * 4 + (threadIdx.x >> 6));
    if (node >= n) return;

    v2f wec2[8];
#pragma unroll
    for (int k = 0; k < 8; k++) {
        wec2[k].x = We[(2 * k) * 64 + lane];
        wec2[k].y = We[(2 * k + 1) * 64 + lane];
    }
    const float LOG2E = 1.4426950408889634f;
    float attl = att[lane] * LOG2E;
    float xrl = xr[(size_t)node * 64 + lane];

    int e0 = __builtin_amdgcn_readfirstlane(offs[node]);
    int e1 = __builtin_amdgcn_readfirstlane(offs[node + 1]);

    float S = 0.f, acc = 0.f;
    int i = e0;

    if ((e1 - e0) & 1) {            // odd count: process slot e0 (self-loop) alone
        int s0 = csr_src[i];
        float4 A0 = csr_ea[i*4+0], A1 = csr_ea[i*4+1],
               A2 = csr_ea[i*4+2], A3 = csr_ea[i*4+3];
        float x0 = (xl + (size_t)s0 * 64)[lane];
        float m0 = EDOT(A0, A1, A2, A3, x0 + xrl);
        m0 = fmaxf(m0, NEG * m0);
        float p0 = red16(m0 * attl);
        float z0 = __builtin_amdgcn_exp2f(p0);
        S = z0; acc = z0 * x0;
        i++;
    }

    if (i < e1) {                    // remaining count is even, >= 2
        int base = i;
        int lastp = ((e1 - i) >> 1) - 1;     // pair indices 0..lastp (uniform)
        int sb00, sb01, sb10, sb11, sb20, sb21;
        float4 ab00, ab01, ab02, ab03, ab04, ab05, ab06, ab07;
        float4 ab10, ab11, ab12, ab13, ab14, ab15, ab16, ab17;
        float4 ab20, ab21, ab22, ab23, ab24, ab25, ab26, ab27;
        float xa0, xc0, xa1, xc1, xa2, xc2;

        int k1 = (1 > lastp) ? lastp : 1;
        int k2 = (2 > lastp) ? lastp : 2;
        LOADS(0, 0); LOADS(k1, 1); LOADS(k2, 2);
        LOADA(0, 0); LOADA(k1, 1);
        GATH(0); GATH(1);

        int t = 0;
        for (;;) {
            PHASE(0, 2); if (t >= lastp) break; ++t;
            PHASE(1, 0); if (t >= lastp) break; ++t;
            PHASE(2, 1); if (t >= lastp) break; ++t;
        }
    }
    out[(size_t)node * 64 + lane] = fmaxf(acc / S + bias[lane], 0.f);
}

// ---------------- fused pool (batch is sorted) + MLP: one block per graph ----------------

__global__ __launch_bounds__(256)
void pool_mlp_kernel(const float* __restrict__ x, const int* __restrict__ batch, int n,
                     const float* __restrict__ W1, const float* __restrict__ b1,
                     const float* __restrict__ W2, const float* __restrict__ b2,
                     float* __restrict__ out) {
    __shared__ float psum[4][64];
    __shared__ float gv[64];
    __shared__ float hid[128];
    __shared__ int bounds[2];

    int g = blockIdx.x;
    int tid = threadIdx.x;
    int wave = tid >> 6, lane = tid & 63;

    if (tid < 2) {
        int target = g + tid;
        int lo = 0, hi = n;
        while (lo < hi) {
            int mid = (lo + hi) >> 1;
            if (batch[mid] < target) lo = mid + 1; else hi = mid;
        }
        bounds[tid] = lo;
    }
    __syncthreads();
    int lo = bounds[0], hi = bounds[1];
    int cnt = hi - lo;

    float s = 0.f;
    for (int nd = lo + wave; nd < hi; nd += 4)
        s += x[(size_t)nd * 64 + lane];
    psum[wave][lane] = s;
    __syncthreads();

    if (tid < 64)
        gv[tid] = (psum[0][tid] + psum[1][tid] + psum[2][tid] + psum[3][tid])
                  / fmaxf((float)cnt, 1.0f);
    __syncthreads();

    if (tid < 128) {
        float h = b1[tid];
        for (int k = 0; k < 64; k++) h += gv[k] * W1[k * 128 + tid];
        hid[tid] = fmaxf(h, 0.f);
    }
    __syncthreads();
    if (tid < 128) {
        float o = b2[tid];
        for (int k = 0; k < 128; k++) o += hid[k] * W2[k * 128 + tid];
        out[g * 128 + tid] = o;
    }
}

// ---------------- launch ----------------

extern "C" void kernel_launch(void* const* d_in, const int* in_sizes, int n_in,
                              void* d_out, int out_size, void* d_ws, size_t ws_size,
                              hipStream_t stream) {
    const float* nf   = (const float*)d_in[0];
    const int*   ei   = (const int*)d_in[1];
    const float* eaw  = (const float*)d_in[2];
    const int*   bat  = (const int*)d_in[3];
    const float* l0_Wl = (const float*)d_in[4];
    const float* l0_bl = (const float*)d_in[5];
    const float* l0_Wr = (const float*)d_in[6];
    const float* l0_br = (const float*)d_in[7];
    const float* l0_We = (const float*)d_in[8];
    const float* l0_att = (const float*)d_in[9];
    const float* l0_bias = (const float*)d_in[10];
    const float* l1_Wl = (const float*)d_in[11];
    const float* l1_bl = (const float*)d_in[12];
    const float* l1_Wr = (const float*)d_in[13];
    const float* l1_br = (const float*)d_in[14];
    const float* l1_We = (const float*)d_in[15];
    const float* l1_att = (const float*)d_in[16];
    const float* l1_bias = (const float*)d_in[17];
    const float* mW1 = (const float*)d_in[18];
    const float* mb1 = (const float*)d_in[19];
    const float* mW2 = (const float*)d_in[20];
    const float* mb2 = (const float*)d_in[21];

    const int N = in_sizes[0] / 64;
    const int E = in_sizes[1] / 2;
    const int G = out_size / OUTD;

    char* w = (char*)d_ws;
    auto carve = [&](size_t bytes) {
        void* p = (void*)w;
        w += (bytes + 255) & ~(size_t)255;
        return p;
    };
    int*    deg     = (int*)carve((size_t)N * 4);
    int*    offs    = (int*)carve((size_t)(N + 1) * 4);
    int*    rank    = (int*)carve((size_t)E * 4);
    int*    bsum    = (int*)carve(4096 * 4);
    int*    csr_src = (int*)carve((size_t)(E + N) * 4);
    v4f*    csr_ea  = (v4f*)carve((size_t)(E + N) * 64);
    float*  xl      = (float*)carve((size_t)N * 64 * 4);
    float*  xr      = (float*)carve((size_t)N * 64 * 4);
    float*  x1      = (float*)carve((size_t)N * 64 * 4);

    hipMemsetAsync(deg, 0, (size_t)N * 4, stream);

    const int* src = ei;
    const int* dst = ei + E;

    hist_kernel<<<(E + 255) / 256, 256, 0, stream>>>(dst, deg, rank, E);

    int nb = (N + 1023) / 1024;
    scan_a<<<nb, 1024, 0, stream>>>(deg, offs, bsum, N);
    scan_b<<<1, 1024, 0, stream>>>(bsum, offs, nb, N);
    scan_c<<<nb, 1024, 0, stream>>>(offs, bsum, N);

    scatter_kernel<<<(E + 255) / 256, 256, 0, stream>>>(src, dst, rank, (const v4f*)eaw,
                                                        offs, csr_src, csr_ea, E);
    loopattr_kernel<<<(N * EDIM + 255) / 256, 256, 0, stream>>>(offs, csr_src,
                                                                (float*)csr_ea, N);

    // layer 0
    dualgemm_kernel<<<(N + 63) / 64, 256, 0, stream>>>(nf, l0_Wl, l0_bl, l0_Wr, l0_br,
                                                       xl, xr, N);
    gat_kernel<<<(N + 3) / 4, 256, 0, stream>>>(offs, csr_src, (const float4*)csr_ea,
                                                xl, xr, l0_We, l0_att, l0_bias, x1, N);
    // layer 1
    dualgemm_kernel<<<(N + 63) / 64, 256, 0, stream>>>(x1, l1_Wl, l1_bl, l1_Wr, l1_br,
                                                       xl, xr, N);
    gat_kernel<<<(N + 3) / 4, 256, 0, stream>>>(offs, csr_src, (const float4*)csr_ea,
                                                xl, xr, l1_We, l1_att, l1_bias, x1, N);

    // fused pool + MLP
    pool_mlp_kernel<<<G, 256, 0, stream>>>(x1, bat, N, mW1, mb1, mW2, mb2, (float*)d_out);
}

// Round 9
// 774.133 us; speedup vs baseline: 1.3860x; 1.0381x over previous
//
#include <hip/hip_runtime.h>
#include <math.h>

// Problem constants (from reference)
#define HID 64      // H*C
#define NH 4
#define NC 16
#define EDIM 16
#define OUTD 128
#define NEG 0.2f

typedef float v4f __attribute__((ext_vector_type(4)));
typedef float v2f __attribute__((ext_vector_type(2)));

// packed fp32 fma (v_pk_fma_f32 on gfx950)
__device__ __forceinline__ v2f pkfma(v2f a, v2f b, v2f c) {
    return __builtin_elementwise_fma(a, b, c);
}

// DPP butterfly add over 16-lane group (quad_perm xor1, xor2, row_ror:4, row_ror:8)
template <int CTRL>
__device__ __forceinline__ float dpp_add(float x) {
    int t = __builtin_amdgcn_update_dpp(0, __float_as_int(x), CTRL, 0xF, 0xF, true);
    return x + __int_as_float(t);
}
__device__ __forceinline__ float red16(float x) {
    x = dpp_add<0xB1>(x);    // quad_perm [1,0,3,2]  (xor 1)
    x = dpp_add<0x4E>(x);    // quad_perm [2,3,0,1]  (xor 2)
    x = dpp_add<0x124>(x);   // row_ror:4
    x = dpp_add<0x128>(x);   // row_ror:8
    return x;
}

// CSR: slot p = int2 {src, eid}. eid < E -> edge attr ea[eid]; eid >= E ->
// self-loop attr la[eid-E]. Slot offs[d] is the self-loop; offs[d]+1.. in-edges.

// ---------------- CSR build ----------------

// hist emits rank[e] (atomicAdd return) so scatter is atomic-free.
__global__ void hist_kernel(const int* __restrict__ dst, int* __restrict__ deg,
                            int* __restrict__ rank, int E) {
    int e = blockIdx.x * 256 + threadIdx.x;
    if (e < E) rank[e] = atomicAdd(&deg[dst[e]], 1);
}

__global__ void scan_a(const int* __restrict__ deg, int* __restrict__ offs,
                       int* __restrict__ bsum, int n) {
    __shared__ int tmp[1024];
    int i = blockIdx.x * 1024 + threadIdx.x;
    int v = (i < n) ? (deg[i] + 1) : 0;      // +1: self-loop slot
    tmp[threadIdx.x] = v;
    __syncthreads();
    for (int off = 1; off < 1024; off <<= 1) {
        int t = (threadIdx.x >= off) ? tmp[threadIdx.x - off] : 0;
        __syncthreads();
        tmp[threadIdx.x] += t;
        __syncthreads();
    }
    if (i < n) offs[i] = tmp[threadIdx.x] - v;   // exclusive
    if (threadIdx.x == 1023) bsum[blockIdx.x] = tmp[1023];
}

__global__ void scan_b(int* __restrict__ bsum, int* __restrict__ offs, int nb, int n) {
    __shared__ int tmp[1024];
    int v = (threadIdx.x < nb) ? bsum[threadIdx.x] : 0;
    tmp[threadIdx.x] = v;
    __syncthreads();
    for (int off = 1; off < 1024; off <<= 1) {
        int t = (threadIdx.x >= off) ? tmp[threadIdx.x - off] : 0;
        __syncthreads();
        tmp[threadIdx.x] += t;
        __syncthreads();
    }
    if (threadIdx.x < nb) bsum[threadIdx.x] = tmp[threadIdx.x] - v;  // exclusive
    if (threadIdx.x == 1023) offs[n] = tmp[1023];                    // total = E + N
}

__global__ void scan_c(int* __restrict__ offs, const int* __restrict__ bsum, int n) {
    int i = blockIdx.x * 1024 + threadIdx.x;
    if (i < n) offs[i] += bsum[blockIdx.x];
}

// scatter: 8 B record per edge (src, eid). No attr payload movement.
__global__ void scatter_kernel(const int* __restrict__ src, const int* __restrict__ dst,
                               const int* __restrict__ rank,
                               const int* __restrict__ offs,
                               int2* __restrict__ csr_rec, int E) {
    int e = blockIdx.x * 256 + threadIdx.x;
    if (e >= E) return;
    int d = dst[e];
    int p = offs[d] + 1 + rank[e];
    csr_rec[p] = make_int2(src[e], e);
}

// self-loop: la[nd] = mean of in-edge attrs (0 if none); stamp self slot record.
// Also pre-warms all of ea into L3 before gat layer 0.
__global__ void loopattr_kernel(const int* __restrict__ offs, int2* __restrict__ csr_rec,
                                const float* __restrict__ ea, float* __restrict__ la,
                                int n, int E) {
    int idx = blockIdx.x * 256 + threadIdx.x;
    if (idx >= n * EDIM) return;
    int nd = idx >> 4, k = idx & 15;
    int e0 = offs[nd], e1 = offs[nd + 1];
    int deg = e1 - e0 - 1;
    float s = 0.f;
    for (int j = e0 + 1; j < e1; j++) {
        int eid = csr_rec[j].y;
        s += ea[(size_t)eid * EDIM + k];
    }
    la[(size_t)nd * EDIM + k] = s / fmaxf((float)deg, 1.0f);
    if (k == 0) csr_rec[e0] = make_int2(nd, E + nd);
}

// ---------------- dual GEMM: xl = x@Wl+bl, xr = x@Wr+br ----------------

__global__ __launch_bounds__(256)
void dualgemm_kernel(const float* __restrict__ x,
                     const float* __restrict__ Wl, const float* __restrict__ bl,
                     const float* __restrict__ Wr, const float* __restrict__ br,
                     float* __restrict__ xl, float* __restrict__ xr, int n) {
    __shared__ float xs[64 * 65];     // [row][k], pad 65
    __shared__ float ws[64 * 128];    // [k][j]: j<64 -> Wl col, j>=64 -> Wr col
    int tid = threadIdx.x;
    int r0 = blockIdx.x * 64;

#pragma unroll
    for (int t = 0; t < 32; t++) {
        int idx = t * 256 + tid;
        int k = idx >> 7, j = idx & 127;
        ws[idx] = (j < 64) ? Wl[k * 64 + j] : Wr[k * 64 + (j - 64)];
    }
#pragma unroll
    for (int t = 0; t < 16; t++) {
        int idx = t * 256 + tid;
        int r = idx >> 6, c = idx & 63;
        float v = (r0 + r < n) ? x[(r0 + r) * 64 + c] : 0.f;
        xs[r * 65 + c] = v;
    }
    __syncthreads();

    int cg = tid & 31;
    int rg = tid >> 5;

    float acc[8][4];
#pragma unroll
    for (int u = 0; u < 8; u++)
#pragma unroll
        for (int v = 0; v < 4; v++) acc[u][v] = 0.f;

    for (int k = 0; k < 64; k++) {
        float4 wv = *(const float4*)&ws[k * 128 + cg * 4];
        float xv[8];
#pragma unroll
        for (int u = 0; u < 8; u++) xv[u] = xs[(rg * 8 + u) * 65 + k];
#pragma unroll
        for (int u = 0; u < 8; u++) {
            acc[u][0] += xv[u] * wv.x;
            acc[u][1] += xv[u] * wv.y;
            acc[u][2] += xv[u] * wv.z;
            acc[u][3] += xv[u] * wv.w;
        }
    }

    int j0 = cg * 4;
    bool isL = (j0 < 64);
    const float* bp = isL ? bl : br;
    float* op = isL ? xl : xr;
    int jj = isL ? j0 : (j0 - 64);
    float4 bv = *(const float4*)&bp[jj];
#pragma unroll
    for (int u = 0; u < 8; u++) {
        int r = r0 + rg * 8 + u;
        if (r < n) {
            float4 o;
            o.x = acc[u][0] + bv.x; o.y = acc[u][1] + bv.y;
            o.z = acc[u][2] + bv.z; o.w = acc[u][3] + bv.w;
            *(float4*)&op[r * 64 + jj] = o;
        }
    }
}

// ---------------- GATv2 layer ----------------
// One wave per dst node, lane = h*16+c. 3-phase modulo-scheduled pipeline:
// records (src,eid) loaded 1+ phases before their gather/attr loads; attrs and
// x-row gathers issue 2 phases before compute. All CSR/attr loads wave-uniform.

#define EDOT(A0, A1, A2, A3, INIT)                                         \
    ({ v2f _a = {(INIT), 0.f};                                             \
       _a = pkfma((v2f){A0.x, A0.y}, wec2[0], _a);                         \
       _a = pkfma((v2f){A0.z, A0.w}, wec2[1], _a);                         \
       _a = pkfma((v2f){A1.x, A1.y}, wec2[2], _a);                         \
       _a = pkfma((v2f){A1.z, A1.w}, wec2[3], _a);                         \
       _a = pkfma((v2f){A2.x, A2.y}, wec2[4], _a);                         \
       _a = pkfma((v2f){A2.z, A2.w}, wec2[5], _a);                         \
       _a = pkfma((v2f){A3.x, A3.y}, wec2[6], _a);                         \
       _a = pkfma((v2f){A3.z, A3.w}, wec2[7], _a);                         \
       _a.x + _a.y; })

#define ATTRP(EID) ((EID) < E ? ea4 + (size_t)(EID) * 4                    \
                              : la4 + (size_t)((EID) - E) * 4)

// load record pair K into buffer BI
#define LOADS(K, BI) do { int _s = base + 2 * (K);                         \
    int2 _r0 = csr_rec[_s], _r1 = csr_rec[_s + 1];                         \
    sb##BI##0 = _r0.x; eb##BI##0 = _r0.y;                                  \
    sb##BI##1 = _r1.x; eb##BI##1 = _r1.y; } while (0)
// load attrs for buffer BI (eids already in BI)
#define LOADA(BI) do {                                                     \
    const float4* _pa = ATTRP(eb##BI##0);                                  \
    const float4* _pb = ATTRP(eb##BI##1);                                  \
    ab##BI##0 = _pa[0]; ab##BI##1 = _pa[1];                                \
    ab##BI##2 = _pa[2]; ab##BI##3 = _pa[3];                                \
    ab##BI##4 = _pb[0]; ab##BI##5 = _pb[1];                                \
    ab##BI##6 = _pb[2]; ab##BI##7 = _pb[3]; } while (0)
// gather x rows for buffer BI (srcs already in BI)
#define GATH(BI) do {                                                      \
    xa##BI = (xl + (size_t)sb##BI##0 * 64)[lane];                          \
    xc##BI = (xl + (size_t)sb##BI##1 * 64)[lane]; } while (0)
// compute pair from buffer BI
#define COMP(BI) do {                                                      \
    float m0 = EDOT(ab##BI##0, ab##BI##1, ab##BI##2, ab##BI##3, xa##BI + xrl); \
    float m1 = EDOT(ab##BI##4, ab##BI##5, ab##BI##6, ab##BI##7, xc##BI + xrl); \
    m0 = fmaxf(m0, NEG * m0);                                              \
    m1 = fmaxf(m1, NEG * m1);                                              \
    float p0 = red16(m0 * attl);                                           \
    float p1 = red16(m1 * attl);                                           \
    float z0 = __builtin_amdgcn_exp2f(p0);                                 \
    float z1 = __builtin_amdgcn_exp2f(p1);                                 \
    S += z0 + z1;                                                          \
    acc = fmaf(z0, xa##BI, fmaf(z1, xc##BI, acc)); } while (0)
// one pipeline phase
#define PHASE(P, Q) do {                                                   \
    int _k3 = t + 3; _k3 = (_k3 > lastp) ? lastp : _k3;                    \
    GATH(Q);                                                               \
    LOADA(Q);                                                              \
    LOADS(_k3, P);                                                         \
    COMP(P); } while (0)

__global__ __launch_bounds__(256)
void gat_kernel(const int* __restrict__ offs, const int2* __restrict__ csr_rec,
                const float* __restrict__ ea, const float* __restrict__ la,
                const float* __restrict__ xl, const float* __restrict__ xr,
                const float* __restrict__ We, const float* __restrict__ att,
                const float* __restrict__ bias, float* __restrict__ out,
                int n, int E) {
    int lane = threadIdx.x & 63;
    int node = __builtin_amdgcn_readfirstlane(blockIdx.x * 4 + (threadIdx.x >> 6));
    if (node >= n) return;

    const float4* ea4 = (const float4*)ea;
    const float4* la4 = (const float4*)la;

    v2f wec2[8];
#pragma unroll
    for (int k = 0; k < 8; k++) {
        wec2[k].x = We[(2 * k) * 64 + lane];
        wec2[k].y = We[(2 * k + 1) * 64 + lane];
    }
    const float LOG2E = 1.4426950408889634f;
    float attl = att[lane] * LOG2E;
    float xrl = xr[(size_t)node * 64 + lane];

    int e0 = __builtin_amdgcn_readfirstlane(offs[node]);
    int e1 = __builtin_amdgcn_readfirstlane(offs[node + 1]);

    float S = 0.f, acc = 0.f;
    int i = e0;

    if ((e1 - e0) & 1) {            // odd count: process slot e0 (self-loop) alone
        int2 r = csr_rec[i];
        int s0 = r.x;
        const float4* ap = ATTRP(r.y);
        float4 A0 = ap[0], A1 = ap[1], A2 = ap[2], A3 = ap[3];
        float x0 = (xl + (size_t)s0 * 64)[lane];
        float m0 = EDOT(A0, A1, A2, A3, x0 + xrl);
        m0 = fmaxf(m0, NEG * m0);
        float p0 = red16(m0 * attl);
        float z0 = __builtin_amdgcn_exp2f(p0);
        S = z0; acc = z0 * x0;
        i++;
    }

    if (i < e1) {                    // remaining count is even, >= 2
        int base = i;
        int lastp = ((e1 - i) >> 1) - 1;     // pair indices 0..lastp (uniform)
        int sb00, sb01, sb10, sb11, sb20, sb21;
        int eb00, eb01, eb10, eb11, eb20, eb21;
        float4 ab00, ab01, ab02, ab03, ab04, ab05, ab06, ab07;
        float4 ab10, ab11, ab12, ab13, ab14, ab15, ab16, ab17;
        float4 ab20, ab21, ab22, ab23, ab24, ab25, ab26, ab27;
        float xa0, xc0, xa1, xc1, xa2, xc2;

        int k1 = (1 > lastp) ? lastp : 1;
        int k2 = (2 > lastp) ? lastp : 2;
        LOADS(0, 0); LOADS(k1, 1); LOADS(k2, 2);
        LOADA(0); LOADA(1);
        GATH(0); GATH(1);

        int t = 0;
        for (;;) {
            PHASE(0, 2); if (t >= lastp) break; ++t;
            PHASE(1, 0); if (t >= lastp) break; ++t;
            PHASE(2, 1); if (t >= lastp) break; ++t;
        }
    }
    out[(size_t)node * 64 + lane] = fmaxf(acc / S + bias[lane], 0.f);
}

// ---------------- fused pool (batch is sorted) + MLP: one block per graph ----------------

__global__ __launch_bounds__(256)
void pool_mlp_kernel(const float* __restrict__ x, const int* __restrict__ batch, int n,
                     const float* __restrict__ W1, const float* __restrict__ b1,
                     const float* __restrict__ W2, const float* __restrict__ b2,
                     float* __restrict__ out) {
    __shared__ float psum[4][64];
    __shared__ float gv[64];
    __shared__ float hid[128];
    __shared__ int bounds[2];

    int g = blockIdx.x;
    int tid = threadIdx.x;
    int wave = tid >> 6, lane = tid & 63;

    if (tid < 2) {
        int target = g + tid;
        int lo = 0, hi = n;
        while (lo < hi) {
            int mid = (lo + hi) >> 1;
            if (batch[mid] < target) lo = mid + 1; else hi = mid;
        }
        bounds[tid] = lo;
    }
    __syncthreads();
    int lo = bounds[0], hi = bounds[1];
    int cnt = hi - lo;

    float s = 0.f;
    for (int nd = lo + wave; nd < hi; nd += 4)
        s += x[(size_t)nd * 64 + lane];
    psum[wave][lane] = s;
    __syncthreads();

    if (tid < 64)
        gv[tid] = (psum[0][tid] + psum[1][tid] + psum[2][tid] + psum[3][tid])
                  / fmaxf((float)cnt, 1.0f);
    __syncthreads();

    if (tid < 128) {
        float h = b1[tid];
        for (int k = 0; k < 64; k++) h += gv[k] * W1[k * 128 + tid];
        hid[tid] = fmaxf(h, 0.f);
    }
    __syncthreads();
    if (tid < 128) {
        float o = b2[tid];
        for (int k = 0; k < 128; k++) o += hid[k] * W2[k * 128 + tid];
        out[g * 128 + tid] = o;
    }
}

// ---------------- launch ----------------

extern "C" void kernel_launch(void* const* d_in, const int* in_sizes, int n_in,
                              void* d_out, int out_size, void* d_ws, size_t ws_size,
                              hipStream_t stream) {
    const float* nf   = (const float*)d_in[0];
    const int*   ei   = (const int*)d_in[1];
    const float* eaw  = (const float*)d_in[2];
    const int*   bat  = (const int*)d_in[3];
    const float* l0_Wl = (const float*)d_in[4];
    const float* l0_bl = (const float*)d_in[5];
    const float* l0_Wr = (const float*)d_in[6];
    const float* l0_br = (const float*)d_in[7];
    const float* l0_We = (const float*)d_in[8];
    const float* l0_att = (const float*)d_in[9];
    const float* l0_bias = (const float*)d_in[10];
    const float* l1_Wl = (const float*)d_in[11];
    const float* l1_bl = (const float*)d_in[12];
    const float* l1_Wr = (const float*)d_in[13];
    const float* l1_br = (const float*)d_in[14];
    const float* l1_We = (const float*)d_in[15];
    const float* l1_att = (const float*)d_in[16];
    const float* l1_bias = (const float*)d_in[17];
    const float* mW1 = (const float*)d_in[18];
    const float* mb1 = (const float*)d_in[19];
    const float* mW2 = (const float*)d_in[20];
    const float* mb2 = (const float*)d_in[21];

    const int N = in_sizes[0] / 64;
    const int E = in_sizes[1] / 2;
    const int G = out_size / OUTD;

    char* w = (char*)d_ws;
    auto carve = [&](size_t bytes) {
        void* p = (void*)w;
        w += (bytes + 255) & ~(size_t)255;
        return p;
    };
    int*    deg     = (int*)carve((size_t)N * 4);
    int*    offs    = (int*)carve((size_t)(N + 1) * 4);
    int*    rank    = (int*)carve((size_t)E * 4);
    int*    bsum    = (int*)carve(4096 * 4);
    int2*   csr_rec = (int2*)carve((size_t)(E + N) * 8);
    float*  la      = (float*)carve((size_t)N * EDIM * 4);
    float*  xl      = (float*)carve((size_t)N * 64 * 4);
    float*  xr      = (float*)carve((size_t)N * 64 * 4);
    float*  x1      = (float*)carve((size_t)N * 64 * 4);

    hipMemsetAsync(deg, 0, (size_t)N * 4, stream);

    const int* src = ei;
    const int* dst = ei + E;

    hist_kernel<<<(E + 255) / 256, 256, 0, stream>>>(dst, deg, rank, E);

    int nb = (N + 1023) / 1024;
    scan_a<<<nb, 1024, 0, stream>>>(deg, offs, bsum, N);
    scan_b<<<1, 1024, 0, stream>>>(bsum, offs, nb, N);
    scan_c<<<nb, 1024, 0, stream>>>(offs, bsum, N);

    scatter_kernel<<<(E + 255) / 256, 256, 0, stream>>>(src, dst, rank, offs,
                                                        csr_rec, E);
    loopattr_kernel<<<(N * EDIM + 255) / 256, 256, 0, stream>>>(offs, csr_rec,
                                                                eaw, la, N, E);

    // layer 0
    dualgemm_kernel<<<(N + 63) / 64, 256, 0, stream>>>(nf, l0_Wl, l0_bl, l0_Wr, l0_br,
                                                       xl, xr, N);
    gat_kernel<<<(N + 3) / 4, 256, 0, stream>>>(offs, csr_rec, eaw, la, xl, xr,
                                                l0_We, l0_att, l0_bias, x1, N, E);
    // layer 1
    dualgemm_kernel<<<(N + 63) / 64, 256, 0, stream>>>(x1, l1_Wl, l1_bl, l1_Wr, l1_br,
                                                       xl, xr, N);
    gat_kernel<<<(N + 3) / 4, 256, 0, stream>>>(offs, csr_rec, eaw, la, xl, xr,
                                                l1_We, l1_att, l1_bias, x1, N, E);

    // fused pool + MLP
    pool_mlp_kernel<<<G, 256, 0, stream>>>(x1, bat, N, mW1, mb1, mW2, mb2, (float*)d_out);
}